// Round 27
// baseline (53.913 us; speedup 1.0000x reference)
//
#include <hip/hip_runtime.h>
#include <hip/hip_bf16.h>

#define D 128
#define H 256
#define NB 32
#define NN 128

typedef __attribute__((ext_vector_type(8))) _Float16 f16x8;
typedef __attribute__((ext_vector_type(4))) float f32x4;
typedef __attribute__((ext_vector_type(16))) float f32x16;
typedef __attribute__((ext_vector_type(2))) unsigned int uint2v;
typedef __attribute__((ext_vector_type(4))) unsigned int uint4v;

__device__ __forceinline__ unsigned short to_f16u(float f) {
  _Float16 h = (_Float16)f;
  return __builtin_bit_cast(unsigned short, h);
}

// packed f32x2 -> f16x2: v_cvt_pkrtz_f16_f32 (verified R17)
__device__ __forceinline__ unsigned cvt_pk_f16(float lo, float hi) {
  unsigned d;
  asm("v_cvt_pkrtz_f16_f32 %0, %1, %2" : "=v"(d) : "v"(lo), "v"(hi));
  return d;
}

// packed f16 add (verified R17); v_pk_add_bf16 does NOT exist (R10)
__device__ __forceinline__ unsigned pk_add_f16(unsigned a, unsigned b) {
  unsigned d;
  asm("v_pk_add_f16 %0, %1, %2" : "=v"(d) : "v"(a), "v"(b));
  return d;
}

// packed relu: signed-i16 max with 0 (verified R7-R17)
__device__ __forceinline__ unsigned pk_relu(unsigned x) {
  unsigned d;
  asm("v_pk_max_i16 %0, %1, %2" : "=v"(d) : "v"(x), "v"(0u));
  return d;
}

// ---------------- Kernel 0: repack all weights to f16 MFMA B-fragment order ----
__global__ __launch_bounds__(512) void k_repack(
    const float* __restrict__ mw1, const float* __restrict__ uw1,
    const float* __restrict__ uw2, const float* __restrict__ mw2,
    unsigned short* __restrict__ w1f, unsigned short* __restrict__ w3f,
    unsigned short* __restrict__ w4f, unsigned short* __restrict__ bw2) {
  const int gt = blockIdx.x * 512 + threadIdx.x;
  const int tile = gt >> 6, l = gt & 63;
  const int lg = l >> 4, l15 = l & 15;
  if (tile < 128) {
    const int ks = tile >> 5, ntg = tile & 31;
#pragma unroll
    for (int e = 0; e < 8; ++e) {
      int k = ks * 32 + lg * 8 + e;
      int col = ntg * 16 + l15;
      float v = (col < 256) ? mw1[k * 256 + col] : mw1[(128 + k) * 256 + (col - 256)];
      w1f[(size_t)(tile * 64 + l) * 8 + e] = to_f16u(v);
    }
  } else if (tile < 256) {
    const int t = tile - 128, ks = t >> 4, ntg = t & 15;
#pragma unroll
    for (int e = 0; e < 8; ++e) {
      int k = ks * 32 + lg * 8 + e;
      w3f[(size_t)(t * 64 + l) * 8 + e] = to_f16u(uw1[k * 256 + ntg * 16 + l15]);
    }
  } else if (tile < 320) {
    const int t = tile - 256, ks = t >> 3, ntg = t & 7;
#pragma unroll
    for (int e = 0; e < 8; ++e) {
      int k = ks * 32 + lg * 8 + e;
      w4f[(size_t)(t * 64 + l) * 8 + e] = to_f16u(uw2[k * 128 + ntg * 16 + l15]);
    }
  } else {
    const int t = tile - 320;            // 0..63: st = t>>2, ntile = t&3
    const int st = t >> 2, ntile = t & 3;
    const int lh = l >> 5, l31 = l & 31;
#pragma unroll
    for (int e = 0; e < 8; ++e) {
      int k = st * 16 + lh * 8 + e;
      bw2[(size_t)(t * 64 + l) * 8 + e] = to_f16u(mw2[k * 128 + ntile * 32 + l31]);
    }
  }
}

// ---------------- Kernel 1: LN*mask -> f16 + both projections (R25) ------------
__global__ __launch_bounds__(512) void k_ln_proj(
    const float* __restrict__ nodes, const float* __restrict__ node_mask,
    const float* __restrict__ ln_g, const float* __restrict__ ln_b,
    const unsigned short* __restrict__ w1f,
    float* __restrict__ xi_p, unsigned short* __restrict__ xjh) {
  const int row0 = blockIdx.x * 16;
  const int tid = threadIdx.x;
  __shared__ unsigned short xh[16 * 128];   // f16, 16B-group swizzled

  {
    const int r = tid >> 5, lane32 = tid & 31, c4 = lane32 * 4;
    float4 v = *(const float4*)(nodes + (size_t)(row0 + r) * D + c4);
    float s1 = v.x + v.y + v.z + v.w;
    float s2 = v.x * v.x + v.y * v.y + v.z * v.z + v.w * v.w;
#pragma unroll
    for (int off = 1; off < 32; off <<= 1) {
      s1 += __shfl_xor(s1, off);
      s2 += __shfl_xor(s2, off);
    }
    float mu = s1 * (1.0f / 128.0f);
    float var = s2 * (1.0f / 128.0f) - mu * mu;
    float rsig = rsqrtf(var + 1e-5f);
    float m = node_mask[row0 + r];
    float4 g4 = *(const float4*)(ln_g + c4);
    float4 b4 = *(const float4*)(ln_b + c4);
    float x0 = ((v.x - mu) * rsig * g4.x + b4.x) * m;
    float x1 = ((v.y - mu) * rsig * g4.y + b4.y) * m;
    float x2 = ((v.z - mu) * rsig * g4.z + b4.z) * m;
    float x3 = ((v.w - mu) * rsig * g4.w + b4.w) * m;
    uint2v u;
    u[0] = cvt_pk_f16(x0, x1);
    u[1] = cvt_pk_f16(x2, x3);
    const int g = (c4 >> 3) ^ (r & 7);    // swizzled 16B-group index
    *(uint2v*)(&xh[r * 128 + g * 8 + (c4 & 7)]) = u;
  }
  __syncthreads();

  const int w8 = tid >> 6, l = tid & 63;
  const int half = w8 >> 2, wq = w8 & 3;
  const int lg = l >> 4, l15 = l & 15;
  f32x4 acc[4];
#pragma unroll
  for (int nt = 0; nt < 4; ++nt) acc[nt] = (f32x4){0.f, 0.f, 0.f, 0.f};

#pragma unroll
  for (int ks = 0; ks < 4; ++ks) {
    const int g = (ks * 4 + lg) ^ (l15 & 7);
    f16x8 a = *(const f16x8*)(&xh[l15 * 128 + g * 8]);
#pragma unroll
    for (int nt = 0; nt < 4; ++nt) {
      const int tile = ks * 32 + half * 16 + wq * 4 + nt;
      f16x8 bf = *(const f16x8*)(w1f + (size_t)(tile * 64 + l) * 8);
      acc[nt] = __builtin_amdgcn_mfma_f32_16x16x32_f16(a, bf, acc[nt], 0, 0, 0);
    }
  }

  if (half == 0) {
#pragma unroll
    for (int nt = 0; nt < 4; ++nt)
#pragma unroll
      for (int r = 0; r < 4; ++r)
        xi_p[(size_t)(row0 + lg * 4 + r) * H + wq * 64 + nt * 16 + l15] = acc[nt][r];
  } else {
#pragma unroll
    for (int nt = 0; nt < 4; ++nt)
#pragma unroll
      for (int r = 0; r < 4; ++r)
        xjh[(size_t)(row0 + lg * 4 + r) * H + wq * 64 + nt * 16 + l15] = to_f16u(acc[nt][r]);
  }
}

// ---------------- Kernel 2: msgs GEMM (persistent) + FUSED update MLP ----------
// R27 = R26 with aggL declared as a FIRST-CLASS __shared__ float array so the
// compiler sees addrspace(3) and emits ds_add_f32 (R26's pool-cast atomic
// likely became a flat atomic -- undefined on LDS -> lost adds, absmax 1.47).
// Zero syncs in the 4-item loop; 8 barriers deleted vs R25.
__global__ __launch_bounds__(1024, 4) void k_msgs(
    const float* __restrict__ xi_p, const unsigned short* __restrict__ xjh,
    const unsigned short* __restrict__ bw2g, const float* __restrict__ mb1,
    const float* __restrict__ mb2, const float* __restrict__ node_mask,
    const float* __restrict__ nodes, const unsigned short* __restrict__ w3f,
    const float* __restrict__ ub1, const unsigned short* __restrict__ w4f,
    const float* __restrict__ ub2, float* __restrict__ out) {
  const int blk = blockIdx.x;
  const int b = blk >> 3;
  const int i16 = (blk & 7) * 16;        // first row of this block's 16
  const int tid = threadIdx.x;           // 0..1023
  const int w = tid >> 6, l = tid & 63;  // 16 waves
  const int ipair = w >> 3;              // 0..1
  const int jslab = (w & 7) >> 1;        // 0..3
  const int nh = w & 1;                  // 0..1
  const int jbase = jslab * 32;
  const int l31 = l & 31, lh = l >> 5;
  const int lg = (l >> 4) & 3, l15 = l & 15;

  __shared__ __align__(16) char smem[140288];  // 137 KB pool
  __shared__ float aggL[16 * 128];             // 8 KB, first-class LDS (ds_add)
  unsigned short* bw2s = (unsigned short*)smem;            // 64 KB
  unsigned short* xjs  = (unsigned short*)(smem + 65536);  // 64 KB
  unsigned* csAll      = (unsigned*)(smem + 131072);       // 8 KB [16][128]
  float* mb2s          = (float*)(smem + 139264);          // 512 B
  float* maskS         = (float*)(smem + 139776);          // 512 B
  // upd-phase overlay (xjs dead after main loop):
  unsigned short* ah   = (unsigned short*)(smem + 65536);  // 8 KB [16][256]
  unsigned short* uh   = (unsigned short*)(smem + 73728);  // 8 KB [16][256]
  float* nsf           = (float*)(smem + 81920);           // 8 KB [16][128]
  float* msk           = (float*)(smem + 90112);           // 64 B

  {
    const uint4v* src = (const uint4v*)bw2g;
    uint4v* dst = (uint4v*)bw2s;
#pragma unroll
    for (int c = 0; c < 4; ++c) dst[c * 1024 + tid] = src[c * 1024 + tid];
  }
  {
    // Stage xjh[b] (128 j x 256 k f16) into fragment-tile order (once per blk)
    const int jj = tid & 127;
    const int qq = tid >> 7;             // 0..7 -> chunks qq*4 .. qq*4+3
    const int js = jj >> 5, j31 = jj & 31;
    const unsigned short* grow = xjh + (size_t)(b * NN + jj) * H;
    uint4v* dst = (uint4v*)xjs;
#pragma unroll
    for (int r = 0; r < 4; ++r) {
      const int c = qq * 4 + r;          // 0..31
      const int st = c >> 1, lhh = c & 1;
      dst[((js * 16 + st) * 2 + lhh) * 32 + j31] =
          *(const uint4v*)(grow + c * 8);
    }
  }
  {
    // csAll: packed (xi_p + mb1) f16 pairs for this block's 16 i rows.
#pragma unroll
    for (int c = 0; c < 2; ++c) {
      int idx = c * 1024 + tid;          // 0..2047
      int ii = idx >> 7, p = idx & 127;
      float2 xi2 = *(const float2*)(xi_p + (size_t)(b * NN + i16 + ii) * H + 2 * p);
      float2 mbv = *(const float2*)(mb1 + 2 * p);
      csAll[ii * 128 + p] = cvt_pk_f16(xi2.x + mbv.x, xi2.y + mbv.y);
    }
  }
  aggL[tid] = 0.f;
  aggL[tid + 1024] = 0.f;
  if (tid < 128) { mb2s[tid] = mb2[tid]; maskS[tid] = node_mask[b * NN + tid]; }
  __syncthreads();

  const uint4v* bfrag = (const uint4v*)bw2s;
  const uint4v* xfrag = (const uint4v*)xjs;

  for (int t = 0; t < 4; ++t) {
    f32x16 acc[2][2];                    // [i-of-pair][ntile]
#pragma unroll
    for (int ii = 0; ii < 2; ++ii)
#pragma unroll
      for (int nt = 0; nt < 2; ++nt)
#pragma unroll
        for (int r = 0; r < 16; ++r) acc[ii][nt][r] = 0.f;

    const int ia = (t * 4 + ipair * 2) * 128;      // csAll row offsets
#pragma unroll
    for (int st = 0; st < 16; ++st) {
      const int kb = st * 16 + lh * 8;   // f16-elem k offset
      uint4v xu = xfrag[((jslab * 16 + st) * 2 + lh) * 32 + l31];
      uint4v cc0 = *(const uint4v*)(&csAll[ia + (kb >> 1)]);
      uint4v cc1 = *(const uint4v*)(&csAll[ia + 128 + (kb >> 1)]);
      uint4v a0, a1;
#pragma unroll
      for (int p = 0; p < 4; ++p) {
        a0[p] = pk_relu(pk_add_f16(xu[p], cc0[p]));
        a1[p] = pk_relu(pk_add_f16(xu[p], cc1[p]));
      }
      f16x8 af0 = __builtin_bit_cast(f16x8, a0);
      f16x8 af1 = __builtin_bit_cast(f16x8, a1);
#pragma unroll
      for (int nt = 0; nt < 2; ++nt) {
        f16x8 bf = __builtin_bit_cast(f16x8, bfrag[(st * 4 + nh * 2 + nt) * 64 + l]);
        acc[0][nt] = __builtin_amdgcn_mfma_f32_32x32x16_f16(af0, bf, acc[0][nt], 0, 0, 0);
        acc[1][nt] = __builtin_amdgcn_mfma_f32_32x32x16_f16(af1, bf, acc[1][nt], 0, 0, 0);
      }
    }

    // Epilogue: relu(acc+mb2)*mask_j, column-sum, ds-atomic add -> aggL.
#pragma unroll
    for (int ii = 0; ii < 2; ++ii)
#pragma unroll
      for (int nt = 0; nt < 2; ++nt) {
        const float bias = mb2s[nh * 64 + nt * 32 + l31];
        float s = 0.f;
#pragma unroll
        for (int reg = 0; reg < 16; ++reg) {
          const int j = jbase + 4 * lh + (reg & 3) + 8 * (reg >> 2);
          s = fmaf(fmaxf(acc[ii][nt][reg] + bias, 0.f), maskS[j], s);
        }
        s += __shfl_xor(s, 32);
        if (l < 32)
          atomicAdd(&aggL[(t * 4 + ipair * 2 + ii) * 128 + nh * 64 + nt * 32 + l31], s);
      }
  }
  __syncthreads();   // all atomics done; xjs dead -> overlay ah/uh/nsf

  // ---------- Fused update MLP for this block's 16 rows ----------
  if (tid < 256) {
    const int r = tid >> 4, l16 = tid & 15, d0 = l16 * 8;
    const size_t grow = (size_t)(b * NN + i16 + r) * D;
    float4 n0 = *(const float4*)(nodes + grow + d0);
    float4 n1 = *(const float4*)(nodes + grow + d0 + 4);
    *(float4*)(&nsf[r * 128 + d0]) = n0;
    *(float4*)(&nsf[r * 128 + d0 + 4]) = n1;
    uint4v u;
    u[0] = cvt_pk_f16(n0.x, n0.y); u[1] = cvt_pk_f16(n0.z, n0.w);
    u[2] = cvt_pk_f16(n1.x, n1.y); u[3] = cvt_pk_f16(n1.z, n1.w);
    int g = l16 ^ (r & 7);
    *(uint4v*)(&ah[r * 256 + g * 8]) = u;
    float4 a0 = *(const float4*)(&aggL[r * 128 + d0]);
    float4 a1 = *(const float4*)(&aggL[r * 128 + d0 + 4]);
    u[0] = cvt_pk_f16(a0.x, a0.y); u[1] = cvt_pk_f16(a0.z, a0.w);
    u[2] = cvt_pk_f16(a1.x, a1.y); u[3] = cvt_pk_f16(a1.z, a1.w);
    g = (16 + l16) ^ (r & 7);
    *(uint4v*)(&ah[r * 256 + g * 8]) = u;
    if (tid < 16) msk[tid] = node_mask[b * NN + i16 + tid];
  }
  __syncthreads();

  // GEMM1: 16x256, K=256; 16 waves, one 16-col tile each.
  {
    f32x4 acc3 = (f32x4){0.f, 0.f, 0.f, 0.f};
#pragma unroll
    for (int ks = 0; ks < 8; ++ks) {
      const int g = (ks * 4 + lg) ^ (l15 & 7);
      f16x8 a = *(const f16x8*)(&ah[l15 * 256 + g * 8]);
      f16x8 bf = *(const f16x8*)(w3f + (size_t)((ks * 16 + w) * 64 + l) * 8);
      acc3 = __builtin_amdgcn_mfma_f32_16x16x32_f16(a, bf, acc3, 0, 0, 0);
    }
    const int col = w * 16 + l15;
    const float bias = ub1[col];
#pragma unroll
    for (int r = 0; r < 4; ++r) {
      const int row = lg * 4 + r;
      const int g2 = (col >> 3) ^ (row & 7);
      uh[row * 256 + g2 * 8 + (col & 7)] = to_f16u(fmaxf(acc3[r] + bias, 0.f));
    }
  }
  __syncthreads();

  // GEMM2: 16x128, K=256; waves 0..7, one 16-col tile each.
  if (w < 8) {
    f32x4 acc4 = (f32x4){0.f, 0.f, 0.f, 0.f};
#pragma unroll
    for (int ks = 0; ks < 8; ++ks) {
      const int g = (ks * 4 + lg) ^ (l15 & 7);
      f16x8 a = *(const f16x8*)(&uh[l15 * 256 + g * 8]);
      f16x8 bf = *(const f16x8*)(w4f + (size_t)((ks * 8 + w) * 64 + l) * 8);
      acc4 = __builtin_amdgcn_mfma_f32_16x16x32_f16(a, bf, acc4, 0, 0, 0);
    }
    const int col = w * 16 + l15;
    const float ub2v = ub2[col];
#pragma unroll
    for (int r = 0; r < 4; ++r) {
      const int row = lg * 4 + r;
      out[(size_t)(b * NN + i16 + row) * D + col] =
          (nsf[row * 128 + col] + acc4[r] + ub2v) * msk[row];
    }
  }
}

extern "C" void kernel_launch(void* const* d_in, const int* in_sizes, int n_in,
                              void* d_out, int out_size, void* d_ws, size_t ws_size,
                              hipStream_t stream) {
  (void)in_sizes; (void)n_in; (void)out_size; (void)ws_size;
  const float* nodes     = (const float*)d_in[0];
  const float* node_mask = (const float*)d_in[1];
  const float* ln_g      = (const float*)d_in[2];
  const float* ln_b      = (const float*)d_in[3];
  const float* mw1       = (const float*)d_in[4];
  const float* mb1       = (const float*)d_in[5];
  const float* mw2       = (const float*)d_in[6];
  const float* mb2       = (const float*)d_in[7];
  const float* uw1       = (const float*)d_in[8];
  const float* ub1       = (const float*)d_in[9];
  const float* uw2       = (const float*)d_in[10];
  const float* ub2       = (const float*)d_in[11];
  float* out = (float*)d_out;

  char* ws = (char*)d_ws;
  float*          xi_p = (float*)(ws);                               // 4 MB
  unsigned short* xjh  = (unsigned short*)(ws + ((size_t)4 << 20));  // 2 MB
  unsigned short* bw2  = (unsigned short*)(ws + ((size_t)6 << 20));            // 64 KB
  unsigned short* w1f  = (unsigned short*)(ws + ((size_t)6 << 20) + (64 << 10));   // 128 KB
  unsigned short* w3f  = (unsigned short*)(ws + ((size_t)6 << 20) + (192 << 10));  // 128 KB
  unsigned short* w4f  = (unsigned short*)(ws + ((size_t)6 << 20) + (320 << 10));  // 64 KB

  k_repack<<<48, 512, 0, stream>>>(mw1, uw1, uw2, mw2, w1f, w3f, w4f, bw2);
  k_ln_proj<<<256, 512, 0, stream>>>(nodes, node_mask, ln_g, ln_b, w1f, xi_p, xjh);
  k_msgs<<<256, 1024, 0, stream>>>(xi_p, xjh, bw2, mb1, mb2, node_mask,
                                   nodes, w3f, ub1, w4f, ub2, out);
}

// Round 28
// 52.578 us; speedup vs baseline: 1.0254x; 1.0254x over previous
//
#include <hip/hip_runtime.h>
#include <hip/hip_bf16.h>

#define D 128
#define H 256
#define NB 32
#define NN 128

typedef __attribute__((ext_vector_type(8))) _Float16 f16x8;
typedef __attribute__((ext_vector_type(4))) float f32x4;
typedef __attribute__((ext_vector_type(16))) float f32x16;
typedef __attribute__((ext_vector_type(2))) unsigned int uint2v;
typedef __attribute__((ext_vector_type(4))) unsigned int uint4v;

__device__ __forceinline__ unsigned short to_f16u(float f) {
  _Float16 h = (_Float16)f;
  return __builtin_bit_cast(unsigned short, h);
}

// packed f32x2 -> f16x2: v_cvt_pkrtz_f16_f32 (verified R17)
__device__ __forceinline__ unsigned cvt_pk_f16(float lo, float hi) {
  unsigned d;
  asm("v_cvt_pkrtz_f16_f32 %0, %1, %2" : "=v"(d) : "v"(lo), "v"(hi));
  return d;
}

// packed f16 add (verified R17); v_pk_add_bf16 does NOT exist (R10)
__device__ __forceinline__ unsigned pk_add_f16(unsigned a, unsigned b) {
  unsigned d;
  asm("v_pk_add_f16 %0, %1, %2" : "=v"(d) : "v"(a), "v"(b));
  return d;
}

// packed relu: signed-i16 max with 0 (verified R7-R17)
__device__ __forceinline__ unsigned pk_relu(unsigned x) {
  unsigned d;
  asm("v_pk_max_i16 %0, %1, %2" : "=v"(d) : "v"(x), "v"(0u));
  return d;
}

// ---------------- Kernel 0: repack all weights to f16 MFMA B-fragment order ----
__global__ __launch_bounds__(512) void k_repack(
    const float* __restrict__ mw1, const float* __restrict__ uw1,
    const float* __restrict__ uw2, const float* __restrict__ mw2,
    unsigned short* __restrict__ w1f, unsigned short* __restrict__ w3f,
    unsigned short* __restrict__ w4f, unsigned short* __restrict__ bw2) {
  const int gt = blockIdx.x * 512 + threadIdx.x;
  const int tile = gt >> 6, l = gt & 63;
  const int lg = l >> 4, l15 = l & 15;
  if (tile < 128) {
    const int ks = tile >> 5, ntg = tile & 31;
#pragma unroll
    for (int e = 0; e < 8; ++e) {
      int k = ks * 32 + lg * 8 + e;
      int col = ntg * 16 + l15;
      float v = (col < 256) ? mw1[k * 256 + col] : mw1[(128 + k) * 256 + (col - 256)];
      w1f[(size_t)(tile * 64 + l) * 8 + e] = to_f16u(v);
    }
  } else if (tile < 256) {
    const int t = tile - 128, ks = t >> 4, ntg = t & 15;
#pragma unroll
    for (int e = 0; e < 8; ++e) {
      int k = ks * 32 + lg * 8 + e;
      w3f[(size_t)(t * 64 + l) * 8 + e] = to_f16u(uw1[k * 256 + ntg * 16 + l15]);
    }
  } else if (tile < 320) {
    const int t = tile - 256, ks = t >> 3, ntg = t & 7;
#pragma unroll
    for (int e = 0; e < 8; ++e) {
      int k = ks * 32 + lg * 8 + e;
      w4f[(size_t)(t * 64 + l) * 8 + e] = to_f16u(uw2[k * 128 + ntg * 16 + l15]);
    }
  } else {
    const int t = tile - 320;            // 0..63: st = t>>2, ntile = t&3
    const int st = t >> 2, ntile = t & 3;
    const int lh = l >> 5, l31 = l & 31;
#pragma unroll
    for (int e = 0; e < 8; ++e) {
      int k = st * 16 + lh * 8 + e;
      bw2[(size_t)(t * 64 + l) * 8 + e] = to_f16u(mw2[k * 128 + ntile * 32 + l31]);
    }
  }
}

// ---------------- Kernel 1: LN*mask -> f16 + both projections (R25) ------------
__global__ __launch_bounds__(512) void k_ln_proj(
    const float* __restrict__ nodes, const float* __restrict__ node_mask,
    const float* __restrict__ ln_g, const float* __restrict__ ln_b,
    const unsigned short* __restrict__ w1f,
    float* __restrict__ xi_p, unsigned short* __restrict__ xjh) {
  const int row0 = blockIdx.x * 16;
  const int tid = threadIdx.x;
  __shared__ unsigned short xh[16 * 128];   // f16, 16B-group swizzled

  {
    const int r = tid >> 5, lane32 = tid & 31, c4 = lane32 * 4;
    float4 v = *(const float4*)(nodes + (size_t)(row0 + r) * D + c4);
    float s1 = v.x + v.y + v.z + v.w;
    float s2 = v.x * v.x + v.y * v.y + v.z * v.z + v.w * v.w;
#pragma unroll
    for (int off = 1; off < 32; off <<= 1) {
      s1 += __shfl_xor(s1, off);
      s2 += __shfl_xor(s2, off);
    }
    float mu = s1 * (1.0f / 128.0f);
    float var = s2 * (1.0f / 128.0f) - mu * mu;
    float rsig = rsqrtf(var + 1e-5f);
    float m = node_mask[row0 + r];
    float4 g4 = *(const float4*)(ln_g + c4);
    float4 b4 = *(const float4*)(ln_b + c4);
    float x0 = ((v.x - mu) * rsig * g4.x + b4.x) * m;
    float x1 = ((v.y - mu) * rsig * g4.y + b4.y) * m;
    float x2 = ((v.z - mu) * rsig * g4.z + b4.z) * m;
    float x3 = ((v.w - mu) * rsig * g4.w + b4.w) * m;
    uint2v u;
    u[0] = cvt_pk_f16(x0, x1);
    u[1] = cvt_pk_f16(x2, x3);
    const int g = (c4 >> 3) ^ (r & 7);    // swizzled 16B-group index
    *(uint2v*)(&xh[r * 128 + g * 8 + (c4 & 7)]) = u;
  }
  __syncthreads();

  const int w8 = tid >> 6, l = tid & 63;
  const int half = w8 >> 2, wq = w8 & 3;
  const int lg = l >> 4, l15 = l & 15;
  f32x4 acc[4];
#pragma unroll
  for (int nt = 0; nt < 4; ++nt) acc[nt] = (f32x4){0.f, 0.f, 0.f, 0.f};

#pragma unroll
  for (int ks = 0; ks < 4; ++ks) {
    const int g = (ks * 4 + lg) ^ (l15 & 7);
    f16x8 a = *(const f16x8*)(&xh[l15 * 128 + g * 8]);
#pragma unroll
    for (int nt = 0; nt < 4; ++nt) {
      const int tile = ks * 32 + half * 16 + wq * 4 + nt;
      f16x8 bf = *(const f16x8*)(w1f + (size_t)(tile * 64 + l) * 8);
      acc[nt] = __builtin_amdgcn_mfma_f32_16x16x32_f16(a, bf, acc[nt], 0, 0, 0);
    }
  }

  if (half == 0) {
#pragma unroll
    for (int nt = 0; nt < 4; ++nt)
#pragma unroll
      for (int r = 0; r < 4; ++r)
        xi_p[(size_t)(row0 + lg * 4 + r) * H + wq * 64 + nt * 16 + l15] = acc[nt][r];
  } else {
#pragma unroll
    for (int nt = 0; nt < 4; ++nt)
#pragma unroll
      for (int r = 0; r < 4; ++r)
        xjh[(size_t)(row0 + lg * 4 + r) * H + wq * 64 + nt * 16 + l15] = to_f16u(acc[nt][r]);
  }
}

// ---------------- Kernel 2: msgs GEMM (persistent) + FUSED update MLP ----------
// R28 = R25 (measured best, 52.36us) with one free elision: the trailing
// barrier of the LAST item (t=3) is skipped (post-loop barrier follows
// immediately; waveAgg untouched between them). R26/R27 atomics condemned
// (wrong via pool-cast; slow via ds_add RMW serialization).
__global__ __launch_bounds__(1024, 4) void k_msgs(
    const float* __restrict__ xi_p, const unsigned short* __restrict__ xjh,
    const unsigned short* __restrict__ bw2g, const float* __restrict__ mb1,
    const float* __restrict__ mb2, const float* __restrict__ node_mask,
    const float* __restrict__ nodes, const unsigned short* __restrict__ w3f,
    const float* __restrict__ ub1, const unsigned short* __restrict__ w4f,
    const float* __restrict__ ub2, float* __restrict__ out) {
  const int blk = blockIdx.x;
  const int b = blk >> 3;
  const int i16 = (blk & 7) * 16;        // first row of this block's 16
  const int tid = threadIdx.x;           // 0..1023
  const int w = tid >> 6, l = tid & 63;  // 16 waves
  const int ipair = w >> 3;              // 0..1
  const int jslab = (w & 7) >> 1;        // 0..3
  const int nh = w & 1;                  // 0..1
  const int jbase = jslab * 32;
  const int l31 = l & 31, lh = l >> 5;
  const int lg = (l >> 4) & 3, l15 = l & 15;

  __shared__ __align__(16) char smem[156672];  // 153 KB pool
  unsigned short* bw2s = (unsigned short*)smem;            // 64 KB
  unsigned short* xjs  = (unsigned short*)(smem + 65536);  // 64 KB
  unsigned* csAll      = (unsigned*)(smem + 131072);       // 8 KB [16][128]
  float* mb2s          = (float*)(smem + 139264);          // 512 B
  float* maskS         = (float*)(smem + 139776);          // 512 B
  float* waveAgg       = (float*)(smem + 140288);          // 8 KB [16][2][64]
  float* aggL          = (float*)(smem + 148480);          // 8 KB [16][128]
  // upd-phase overlay (xjs dead after main loop):
  unsigned short* ah   = (unsigned short*)(smem + 65536);  // 8 KB [16][256]
  unsigned short* uh   = (unsigned short*)(smem + 73728);  // 8 KB [16][256]
  float* nsf           = (float*)(smem + 81920);           // 8 KB [16][128]
  float* msk           = (float*)(smem + 90112);           // 64 B

  {
    const uint4v* src = (const uint4v*)bw2g;
    uint4v* dst = (uint4v*)bw2s;
#pragma unroll
    for (int c = 0; c < 4; ++c) dst[c * 1024 + tid] = src[c * 1024 + tid];
  }
  {
    // Stage xjh[b] (128 j x 256 k f16) into fragment-tile order (once per blk)
    const int jj = tid & 127;
    const int qq = tid >> 7;             // 0..7 -> chunks qq*4 .. qq*4+3
    const int js = jj >> 5, j31 = jj & 31;
    const unsigned short* grow = xjh + (size_t)(b * NN + jj) * H;
    uint4v* dst = (uint4v*)xjs;
#pragma unroll
    for (int r = 0; r < 4; ++r) {
      const int c = qq * 4 + r;          // 0..31
      const int st = c >> 1, lhh = c & 1;
      dst[((js * 16 + st) * 2 + lhh) * 32 + j31] =
          *(const uint4v*)(grow + c * 8);
    }
  }
  {
    // csAll: packed (xi_p + mb1) f16 pairs for this block's 16 i rows.
#pragma unroll
    for (int c = 0; c < 2; ++c) {
      int idx = c * 1024 + tid;          // 0..2047
      int ii = idx >> 7, p = idx & 127;
      float2 xi2 = *(const float2*)(xi_p + (size_t)(b * NN + i16 + ii) * H + 2 * p);
      float2 mbv = *(const float2*)(mb1 + 2 * p);
      csAll[ii * 128 + p] = cvt_pk_f16(xi2.x + mbv.x, xi2.y + mbv.y);
    }
  }
  if (tid < 128) { mb2s[tid] = mb2[tid]; maskS[tid] = node_mask[b * NN + tid]; }
  __syncthreads();

  const uint4v* bfrag = (const uint4v*)bw2s;
  const uint4v* xfrag = (const uint4v*)xjs;

  for (int t = 0; t < 4; ++t) {
    f32x16 acc[2][2];                    // [i-of-pair][ntile]
#pragma unroll
    for (int ii = 0; ii < 2; ++ii)
#pragma unroll
      for (int nt = 0; nt < 2; ++nt)
#pragma unroll
        for (int r = 0; r < 16; ++r) acc[ii][nt][r] = 0.f;

    const int ia = (t * 4 + ipair * 2) * 128;      // csAll row offsets
#pragma unroll
    for (int st = 0; st < 16; ++st) {
      const int kb = st * 16 + lh * 8;   // f16-elem k offset
      uint4v xu = xfrag[((jslab * 16 + st) * 2 + lh) * 32 + l31];
      uint4v cc0 = *(const uint4v*)(&csAll[ia + (kb >> 1)]);
      uint4v cc1 = *(const uint4v*)(&csAll[ia + 128 + (kb >> 1)]);
      uint4v a0, a1;
#pragma unroll
      for (int p = 0; p < 4; ++p) {
        a0[p] = pk_relu(pk_add_f16(xu[p], cc0[p]));
        a1[p] = pk_relu(pk_add_f16(xu[p], cc1[p]));
      }
      f16x8 af0 = __builtin_bit_cast(f16x8, a0);
      f16x8 af1 = __builtin_bit_cast(f16x8, a1);
#pragma unroll
      for (int nt = 0; nt < 2; ++nt) {
        f16x8 bf = __builtin_bit_cast(f16x8, bfrag[(st * 4 + nh * 2 + nt) * 64 + l]);
        acc[0][nt] = __builtin_amdgcn_mfma_f32_32x32x16_f16(af0, bf, acc[0][nt], 0, 0, 0);
        acc[1][nt] = __builtin_amdgcn_mfma_f32_32x32x16_f16(af1, bf, acc[1][nt], 0, 0, 0);
      }
    }

    // Epilogue: relu(acc+mb2)*mask_j, column-sum -> aggL (LDS).
#pragma unroll
    for (int ii = 0; ii < 2; ++ii)
#pragma unroll
      for (int nt = 0; nt < 2; ++nt) {
        const float bias = mb2s[nh * 64 + nt * 32 + l31];
        float s = 0.f;
#pragma unroll
        for (int reg = 0; reg < 16; ++reg) {
          const int j = jbase + 4 * lh + (reg & 3) + 8 * (reg >> 2);
          s = fmaf(fmaxf(acc[ii][nt][reg] + bias, 0.f), maskS[j], s);
        }
        s += __shfl_xor(s, 32);
        if (l < 32) waveAgg[((w * 2) + ii) * 64 + nt * 32 + l31] = s;
      }
    __syncthreads();
    if (tid < 512) {
      const int ii4 = tid >> 7, col = tid & 127;  // 4 i's x 128 cols
      const int ipq = ii4 >> 1, iwi = ii4 & 1;
      const int nh2 = col >> 6, c6 = col & 63;
      aggL[(t * 4 + ii4) * 128 + col] =
          waveAgg[((ipq * 8 + 0 + nh2) * 2 + iwi) * 64 + c6] +
          waveAgg[((ipq * 8 + 2 + nh2) * 2 + iwi) * 64 + c6] +
          waveAgg[((ipq * 8 + 4 + nh2) * 2 + iwi) * 64 + c6] +
          waveAgg[((ipq * 8 + 6 + nh2) * 2 + iwi) * 64 + c6];
    }
    if (t < 3) __syncthreads();          // last item's barrier elided (post-loop sync follows)
  }
  __syncthreads();   // aggL complete; xjs dead -> overlay ah/uh/nsf

  // ---------- Fused update MLP for this block's 16 rows ----------
  if (tid < 256) {
    const int r = tid >> 4, l16 = tid & 15, d0 = l16 * 8;
    const size_t grow = (size_t)(b * NN + i16 + r) * D;
    float4 n0 = *(const float4*)(nodes + grow + d0);
    float4 n1 = *(const float4*)(nodes + grow + d0 + 4);
    *(float4*)(&nsf[r * 128 + d0]) = n0;
    *(float4*)(&nsf[r * 128 + d0 + 4]) = n1;
    uint4v u;
    u[0] = cvt_pk_f16(n0.x, n0.y); u[1] = cvt_pk_f16(n0.z, n0.w);
    u[2] = cvt_pk_f16(n1.x, n1.y); u[3] = cvt_pk_f16(n1.z, n1.w);
    int g = l16 ^ (r & 7);
    *(uint4v*)(&ah[r * 256 + g * 8]) = u;
    float4 a0 = *(const float4*)(&aggL[r * 128 + d0]);
    float4 a1 = *(const float4*)(&aggL[r * 128 + d0 + 4]);
    u[0] = cvt_pk_f16(a0.x, a0.y); u[1] = cvt_pk_f16(a0.z, a0.w);
    u[2] = cvt_pk_f16(a1.x, a1.y); u[3] = cvt_pk_f16(a1.z, a1.w);
    g = (16 + l16) ^ (r & 7);
    *(uint4v*)(&ah[r * 256 + g * 8]) = u;
    if (tid < 16) msk[tid] = node_mask[b * NN + i16 + tid];
  }
  __syncthreads();

  // GEMM1: 16x256, K=256; 16 waves, one 16-col tile each.
  {
    f32x4 acc3 = (f32x4){0.f, 0.f, 0.f, 0.f};
#pragma unroll
    for (int ks = 0; ks < 8; ++ks) {
      const int g = (ks * 4 + lg) ^ (l15 & 7);
      f16x8 a = *(const f16x8*)(&ah[l15 * 256 + g * 8]);
      f16x8 bf = *(const f16x8*)(w3f + (size_t)((ks * 16 + w) * 64 + l) * 8);
      acc3 = __builtin_amdgcn_mfma_f32_16x16x32_f16(a, bf, acc3, 0, 0, 0);
    }
    const int col = w * 16 + l15;
    const float bias = ub1[col];
#pragma unroll
    for (int r = 0; r < 4; ++r) {
      const int row = lg * 4 + r;
      const int g2 = (col >> 3) ^ (row & 7);
      uh[row * 256 + g2 * 8 + (col & 7)] = to_f16u(fmaxf(acc3[r] + bias, 0.f));
    }
  }
  __syncthreads();

  // GEMM2: 16x128, K=256; waves 0..7, one 16-col tile each.
  if (w < 8) {
    f32x4 acc4 = (f32x4){0.f, 0.f, 0.f, 0.f};
#pragma unroll
    for (int ks = 0; ks < 8; ++ks) {
      const int g = (ks * 4 + lg) ^ (l15 & 7);
      f16x8 a = *(const f16x8*)(&uh[l15 * 256 + g * 8]);
      f16x8 bf = *(const f16x8*)(w4f + (size_t)((ks * 8 + w) * 64 + l) * 8);
      acc4 = __builtin_amdgcn_mfma_f32_16x16x32_f16(a, bf, acc4, 0, 0, 0);
    }
    const int col = w * 16 + l15;
    const float ub2v = ub2[col];
#pragma unroll
    for (int r = 0; r < 4; ++r) {
      const int row = lg * 4 + r;
      out[(size_t)(b * NN + i16 + row) * D + col] =
          (nsf[row * 128 + col] + acc4[r] + ub2v) * msk[row];
    }
  }
}

extern "C" void kernel_launch(void* const* d_in, const int* in_sizes, int n_in,
                              void* d_out, int out_size, void* d_ws, size_t ws_size,
                              hipStream_t stream) {
  (void)in_sizes; (void)n_in; (void)out_size; (void)ws_size;
  const float* nodes     = (const float*)d_in[0];
  const float* node_mask = (const float*)d_in[1];
  const float* ln_g      = (const float*)d_in[2];
  const float* ln_b      = (const float*)d_in[3];
  const float* mw1       = (const float*)d_in[4];
  const float* mb1       = (const float*)d_in[5];
  const float* mw2       = (const float*)d_in[6];
  const float* mb2       = (const float*)d_in[7];
  const float* uw1       = (const float*)d_in[8];
  const float* ub1       = (const float*)d_in[9];
  const float* uw2       = (const float*)d_in[10];
  const float* ub2       = (const float*)d_in[11];
  float* out = (float*)d_out;

  char* ws = (char*)d_ws;
  float*          xi_p = (float*)(ws);                               // 4 MB
  unsigned short* xjh  = (unsigned short*)(ws + ((size_t)4 << 20));  // 2 MB
  unsigned short* bw2  = (unsigned short*)(ws + ((size_t)6 << 20));            // 64 KB
  unsigned short* w1f  = (unsigned short*)(ws + ((size_t)6 << 20) + (64 << 10));   // 128 KB
  unsigned short* w3f  = (unsigned short*)(ws + ((size_t)6 << 20) + (192 << 10));  // 128 KB
  unsigned short* w4f  = (unsigned short*)(ws + ((size_t)6 << 20) + (320 << 10));  // 64 KB

  k_repack<<<48, 512, 0, stream>>>(mw1, uw1, uw2, mw2, w1f, w3f, w4f, bw2);
  k_ln_proj<<<256, 512, 0, stream>>>(nodes, node_mask, ln_g, ln_b, w1f, xi_p, xjh);
  k_msgs<<<256, 1024, 0, stream>>>(xi_p, xjh, bw2, mb1, mb2, node_mask,
                                   nodes, w3f, ub1, w4f, ub2, out);
}